// Round 14
// baseline (70.620 us; speedup 1.0000x reference)
//
#include <hip/hip_runtime.h>

// Fully-fused cascaded-biquad IIR (DF2T) via linear state-space chunking.
// R14 = R13 dense-staged skeleton with a barrier-free scan:
//   P1: stage half-tile (global_load_lds, 128B-dense, pre-swizzled src)
//       -> per-chunk state from zero (wave-local vmcnt/lgkm sync)
//   SCAN: levels 0..5 in-wave via __shfl; ONE raw s_barrier (lgkm-only);
//         cross-wave prefix via Bnd[8] + M^64 folds; z = M^lane*P by
//         binary-bit mat-vec steps. Per-wave LDS copies of Ms[0..6].
//   P4: HT0 staged BEFORE the scan (scan hides the load latency);
//       transpose-out to regs -> HT1 gll issued before HT0 stores ->
//       counted vmcnt(8) -> HT1 compute. One __syncthreads total: zero
//       (raw barrier only).

namespace {
constexpr int NS     = 4;
constexpr int BATCH  = 512;
constexpr int TLEN   = 32768;      // 2^15
constexpr int NSTATE = 8;
constexpr int P      = 512;        // chunks per batch = threads per block
constexpr int L      = TLEN / P;   // 64 steps per chunk
constexpr int LQ     = L / 4;      // 16 float4 per chunk
constexpr int NMS    = 7;          // Ms[d] = M^(2^d), d=0..6 (M = A^L)
}

#if defined(__has_builtin)
#  if __has_builtin(__builtin_amdgcn_global_load_lds)
#    define USE_GLL 1
#  endif
#endif
#ifndef USE_GLL
#  define USE_GLL 0
#endif

#define WAIT_VM0 do { asm volatile("s_waitcnt vmcnt(0)" ::: "memory"); \
                      __builtin_amdgcn_sched_barrier(0); } while (0)
#define WAIT_VM8 do { asm volatile("s_waitcnt vmcnt(8)" ::: "memory"); \
                      __builtin_amdgcn_sched_barrier(0); } while (0)
#define WAIT_LGKM0 do { asm volatile("s_waitcnt lgkmcnt(0)" ::: "memory"); \
                        __builtin_amdgcn_sched_barrier(0); } while (0)

__device__ __forceinline__ void load_coefs(const float* __restrict__ bc,
                                           const float* __restrict__ ac,
                                           float b0[NS], float b1[NS], float b2[NS],
                                           float a1[NS], float a2[NS]) {
#pragma unroll
  for (int k = 0; k < NS; ++k) {
    b0[k] = bc[3 * k];
    b1[k] = bc[3 * k + 1];
    b2[k] = bc[3 * k + 2];
    a1[k] = ac[2 * k];
    a2[k] = ac[2 * k + 1];
  }
}

// One time-step through the 4-section cascade (matches reference exactly).
__device__ __forceinline__ float step_cascade(float sig,
                                              const float b0[NS], const float b1[NS],
                                              const float b2[NS], const float a1[NS],
                                              const float a2[NS],
                                              float s1[NS], float s2[NS]) {
#pragma unroll
  for (int k = 0; k < NS; ++k) {
    float y = fmaf(b0[k], sig, s1[k]);
    s1[k]   = fmaf(-a1[k], y, fmaf(b1[k], sig, s2[k]));
    s2[k]   = fmaf(-a2[k], y, b2[k] * sig);
    sig = y;
  }
  return sig;
}

#define CO b0, b1, b2, a1, a2

__device__ __forceinline__ void adv4(const float4 u,
                                     const float b0[NS], const float b1[NS],
                                     const float b2[NS], const float a1[NS],
                                     const float a2[NS], float s1[NS], float s2[NS]) {
  (void)step_cascade(u.x, CO, s1, s2);
  (void)step_cascade(u.y, CO, s1, s2);
  (void)step_cascade(u.z, CO, s1, s2);
  (void)step_cascade(u.w, CO, s1, s2);
}

__device__ __forceinline__ float4 out4(const float4 u,
                                       const float b0[NS], const float b1[NS],
                                       const float b2[NS], const float a1[NS],
                                       const float a2[NS], float s1[NS], float s2[NS]) {
  float4 y;
  y.x = step_cascade(u.x, CO, s1, s2);
  y.y = step_cascade(u.y, CO, s1, s2);
  y.z = step_cascade(u.z, CO, s1, s2);
  y.w = step_cascade(u.w, CO, s1, s2);
  return y;
}

// Stage one half-tile (64 chunks x 8 f4 = 8KB): linear LDS dest, per-lane
// pre-swizzled global source (R12/R13-validated). Dense 128B lines.
__device__ __forceinline__ void stage_ht(const float4* __restrict__ gx_w,
                                         float4* R, int lane, int ht) {
#if USE_GLL
#pragma unroll
  for (int j = 0; j < 8; ++j) {
    const int cc = j * 8 + (lane >> 3);
    const int qq = lane & 7;
    const float4* g = gx_w + cc * 16 + ht * 8 + (qq ^ (cc & 7));
    __builtin_amdgcn_global_load_lds(
        (const __attribute__((address_space(1))) void*)g,
        (__attribute__((address_space(3))) void*)&R[j * 64], 16, 0, 0);
  }
#else
#pragma unroll
  for (int j = 0; j < 8; ++j) {
    const int cc = j * 8 + (lane >> 3);
    const int qq = lane & 7;
    R[j * 64 + lane] = gx_w[cc * 16 + ht * 8 + (qq ^ (cc & 7))];
  }
#endif
}

__global__ __launch_bounds__(P) void k_fused(const float* __restrict__ x,
                                             const float* __restrict__ bc,
                                             const float* __restrict__ ac,
                                             float* __restrict__ out) {
  __shared__ float4 arena[4096];       // 64KB: wave wv owns [wv*512, +512)
  __shared__ float  Msw[8][NMS][64];   // 14KB: per-wave Ms copies (no x-wave hazard)
  __shared__ float  Bnd[8][8];         // wave-boundary u vectors

  const int t    = threadIdx.x;
  const int lane = t & 63;
  const int wv   = t >> 6;
  const int swz  = lane & 7;
  float4* __restrict__ R = arena + (wv << 9);

  float b0[NS], b1[NS], b2[NS], a1[NS], a2[NS];
  load_coefs(bc, ac, b0, b1, b2, a1, a2);

  const float4* __restrict__ gx_w = reinterpret_cast<const float4*>(x) +
      (size_t)blockIdx.x * (P * LQ) + ((size_t)wv << 10);
  float4* __restrict__ gy_w = reinterpret_cast<float4*>(out) +
      (size_t)blockIdx.x * (P * LQ) + ((size_t)wv << 10);

  // ---- P1 HT0 staging (HBM latency hides under Ms squarings) ----
  stage_ht(gx_w, R, lane, 0);

  // ---- every wave: Ms[d] = (A^L)^(2^d), d=0..6, in-register via __shfl ----
  {
    const int r = lane >> 3, c = lane & 7;
    float p1[NS] = {0.f, 0.f, 0.f, 0.f};
    float p2[NS] = {0.f, 0.f, 0.f, 0.f};
    if (c & 1) p2[c >> 1] = 1.0f; else p1[c >> 1] = 1.0f;
    (void)step_cascade(0.0f, CO, p1, p2);
    float m = (r & 1) ? p2[r >> 1] : p1[r >> 1];  // A element (r,c)
#pragma unroll
    for (int it = 0; it < 12; ++it) {  // A^2 .. A^4096; Ms[d] at it = 5+d
      float acc = 0.0f;
#pragma unroll
      for (int k = 0; k < NSTATE; ++k)
        acc = fmaf(__shfl(m, r * 8 + k), __shfl(m, k * 8 + c), acc);
      m = acc;
      if (it >= 5) Msw[wv][it - 5][lane] = m;  // wave-local store
    }
  }

  // ---- P1: chunk final state from zero, two half-tiles ----
  float s1[NS] = {0.f, 0.f, 0.f, 0.f};
  float s2[NS] = {0.f, 0.f, 0.f, 0.f};
  WAIT_VM0;
#pragma unroll
  for (int q = 0; q < 8; ++q) adv4(R[lane * 8 + (q ^ swz)], CO, s1, s2);
  WAIT_LGKM0;  // WAR: HT0 reads retired before HT1 overwrites
  stage_ht(gx_w, R, lane, 1);
  WAIT_VM0;
#pragma unroll
  for (int q = 0; q < 8; ++q) adv4(R[lane * 8 + (q ^ swz)], CO, s1, s2);

  float w[NSTATE];
#pragma unroll
  for (int k = 0; k < NS; ++k) { w[2 * k] = s1[k]; w[2 * k + 1] = s2[k]; }

  // ---- issue P4 HT0 staging NOW; the whole scan hides its latency ----
  WAIT_LGKM0;  // P1 HT1 reads retired
  stage_ht(gx_w, R, lane, 0);

  // ---- in-wave Kogge-Stone, levels 0..5 (shfl, no barriers) ----
#pragma unroll
  for (int d = 0; d < 6; ++d) {
    const int off = 1 << d;
    const int src = (lane >= off) ? (lane - off) : lane;
    float prev[NSTATE];
#pragma unroll
    for (int r = 0; r < NSTATE; ++r) prev[r] = __shfl(w[r], src);
    if (lane >= off) {
#pragma unroll
      for (int r = 0; r < NSTATE; ++r) {
        float acc = w[r];
#pragma unroll
        for (int k = 0; k < NSTATE; ++k)
          acc = fmaf(Msw[wv][d][r * 8 + k], prev[k], acc);  // uniform: broadcast
        w[r] = acc;
      }
    }
  }

  // ---- wave boundary post + the ONE block barrier (lgkm-only drain) ----
  if (lane == 63) {
#pragma unroll
    for (int r = 0; r < NSTATE; ++r) Bnd[wv][r] = w[r];
  }
  asm volatile("s_waitcnt lgkmcnt(0)" ::: "memory");  // Bnd/Msw visible
  __builtin_amdgcn_s_barrier();                        // raw: vmcnt stays live

  // ---- cross-wave prefix P_wv = Bnd[wv-1] + M^64*P_{wv-1} ----
  float Pv[NSTATE] = {0.f, 0.f, 0.f, 0.f, 0.f, 0.f, 0.f, 0.f};
  for (int j = 0; j < wv; ++j) {  // wave-uniform trip count
    float np[NSTATE];
#pragma unroll
    for (int r = 0; r < NSTATE; ++r) {
      float acc = Bnd[j][r];
#pragma unroll
      for (int k = 0; k < NSTATE; ++k)
        acc = fmaf(Msw[wv][6][r * 8 + k], Pv[k], acc);
      np[r] = acc;
    }
#pragma unroll
    for (int r = 0; r < NSTATE; ++r) Pv[r] = np[r];
  }

  // ---- z = M^lane * P via binary bits; s_init = u_excl + z ----
  float z[NSTATE];
#pragma unroll
  for (int r = 0; r < NSTATE; ++r) z[r] = Pv[r];
#pragma unroll
  for (int b = 0; b < 6; ++b) {
    float zb[NSTATE];
#pragma unroll
    for (int r = 0; r < NSTATE; ++r) {
      float acc = 0.0f;
#pragma unroll
      for (int k = 0; k < NSTATE; ++k)
        acc = fmaf(Msw[wv][b][r * 8 + k], z[k], acc);
      zb[r] = acc;
    }
    const bool bit = (lane >> b) & 1;
#pragma unroll
    for (int r = 0; r < NSTATE; ++r) z[r] = bit ? zb[r] : z[r];
  }
  {
    const int esrc = lane ? lane - 1 : 0;
#pragma unroll
    for (int k = 0; k < NS; ++k) {
      const float ue0 = __shfl(w[2 * k], esrc);
      const float ue1 = __shfl(w[2 * k + 1], esrc);
      s1[k] = (lane ? ue0 : 0.0f) + z[2 * k];
      s2[k] = (lane ? ue1 : 0.0f) + z[2 * k + 1];
    }
  }

  // ---- P4: replay from exact init ----
  WAIT_VM0;  // HT0 staged (issued before the scan)
#pragma unroll
  for (int q = 0; q < 8; ++q) {
    const int s = lane * 8 + (q ^ swz);
    R[s] = out4(R[s], CO, s1, s2);  // in-place: own slots only
  }
  WAIT_LGKM0;  // in-place writes committed
  float4 v[8];
#pragma unroll
  for (int j = 0; j < 8; ++j) v[j] = R[j * 64 + lane];  // transpose-out to regs
  WAIT_LGKM0;  // reads landed before gll overwrites the region
  stage_ht(gx_w, R, lane, 1);  // HT1 loads issued BEFORE HT0 stores
#pragma unroll
  for (int j = 0; j < 8; ++j) {
    const int cc = j * 8 + (lane >> 3);
    const int qq = lane & 7;
    gy_w[cc * 16 + (qq ^ (cc & 7))] = v[j];  // dense 128B lines
  }
  WAIT_VM8;  // retires the 8 gll (older), leaves the 8 stores in flight
#pragma unroll
  for (int q = 0; q < 8; ++q) {
    const int s = lane * 8 + (q ^ swz);
    R[s] = out4(R[s], CO, s1, s2);
  }
  WAIT_LGKM0;
#pragma unroll
  for (int j = 0; j < 8; ++j) v[j] = R[j * 64 + lane];
  WAIT_LGKM0;
#pragma unroll
  for (int j = 0; j < 8; ++j) {
    const int cc = j * 8 + (lane >> 3);
    const int qq = lane & 7;
    gy_w[cc * 16 + 8 + (qq ^ (cc & 7))] = v[j];
  }
}

extern "C" void kernel_launch(void* const* d_in, const int* in_sizes, int n_in,
                              void* d_out, int out_size, void* d_ws, size_t ws_size,
                              hipStream_t stream) {
  const float* x  = (const float*)d_in[0];  // (B, T, 1)
  const float* bc = (const float*)d_in[1];  // (NS, 3)
  const float* ac = (const float*)d_in[2];  // (NS, 2)
  float* out = (float*)d_out;               // (B, T, 1)

  k_fused<<<BATCH, P, 0, stream>>>(x, bc, ac, out);
}

// Round 15
// 56.142 us; speedup vs baseline: 1.2579x; 1.2579x over previous
//
#include <hip/hip_runtime.h>

// Fully-fused cascaded-biquad IIR (DF2T) via linear state-space chunking.
// R15 = R13 skeleton (64KB arena, 2 blocks/CU, dense gll staging) with the
// R14-verified scan math at 2KB LDS cost:
//   - in-wave Kogge-Stone levels 0..5 via __shfl (no W array)
//   - Msh[7][64] single copy, written redundantly by ALL waves (benign
//     identical-value race; own-wave lgkm drain suffices to use it)
//   - ONE __syncthreads (vs R13's ~21) for Bnd exchange
//   - cross-wave fold P_wv + z = M^lane * P binary-bit apply
//   - P4 HT0 gll issued BEFORE the scan (latency hidden under scan VALU)
// P4 store path is R13's exact strict-WAIT_VM0 sequence (no counted-vmcnt
// interleave — R14's write-amplification suspect).

namespace {
constexpr int NS     = 4;
constexpr int BATCH  = 512;
constexpr int TLEN   = 32768;      // 2^15
constexpr int NSTATE = 8;
constexpr int P      = 512;        // chunks per batch = threads per block
constexpr int L      = TLEN / P;   // 64 steps per chunk
constexpr int LQ     = L / 4;      // 16 float4 per chunk
constexpr int NMS    = 7;          // Msh[d] = M^(2^d), d=0..6 (M = A^64)
}

#if defined(__has_builtin)
#  if __has_builtin(__builtin_amdgcn_global_load_lds)
#    define USE_GLL 1
#  endif
#endif
#ifndef USE_GLL
#  define USE_GLL 0
#endif

#define WAIT_VM0 do { asm volatile("s_waitcnt vmcnt(0)" ::: "memory"); \
                      __builtin_amdgcn_sched_barrier(0); } while (0)
#define WAIT_LGKM0 do { asm volatile("s_waitcnt lgkmcnt(0)" ::: "memory"); \
                        __builtin_amdgcn_sched_barrier(0); } while (0)

__device__ __forceinline__ void load_coefs(const float* __restrict__ bc,
                                           const float* __restrict__ ac,
                                           float b0[NS], float b1[NS], float b2[NS],
                                           float a1[NS], float a2[NS]) {
#pragma unroll
  for (int k = 0; k < NS; ++k) {
    b0[k] = bc[3 * k];
    b1[k] = bc[3 * k + 1];
    b2[k] = bc[3 * k + 2];
    a1[k] = ac[2 * k];
    a2[k] = ac[2 * k + 1];
  }
}

// One time-step through the 4-section cascade (matches reference exactly).
__device__ __forceinline__ float step_cascade(float sig,
                                              const float b0[NS], const float b1[NS],
                                              const float b2[NS], const float a1[NS],
                                              const float a2[NS],
                                              float s1[NS], float s2[NS]) {
#pragma unroll
  for (int k = 0; k < NS; ++k) {
    float y = fmaf(b0[k], sig, s1[k]);
    s1[k]   = fmaf(-a1[k], y, fmaf(b1[k], sig, s2[k]));
    s2[k]   = fmaf(-a2[k], y, b2[k] * sig);
    sig = y;
  }
  return sig;
}

#define CO b0, b1, b2, a1, a2

__device__ __forceinline__ void adv4(const float4 u,
                                     const float b0[NS], const float b1[NS],
                                     const float b2[NS], const float a1[NS],
                                     const float a2[NS], float s1[NS], float s2[NS]) {
  (void)step_cascade(u.x, CO, s1, s2);
  (void)step_cascade(u.y, CO, s1, s2);
  (void)step_cascade(u.z, CO, s1, s2);
  (void)step_cascade(u.w, CO, s1, s2);
}

__device__ __forceinline__ float4 out4(const float4 u,
                                       const float b0[NS], const float b1[NS],
                                       const float b2[NS], const float a1[NS],
                                       const float a2[NS], float s1[NS], float s2[NS]) {
  float4 y;
  y.x = step_cascade(u.x, CO, s1, s2);
  y.y = step_cascade(u.y, CO, s1, s2);
  y.z = step_cascade(u.z, CO, s1, s2);
  y.w = step_cascade(u.w, CO, s1, s2);
  return y;
}

// Stage one half-tile (64 chunks x 8 f4 = 8KB): linear LDS dest, per-lane
// pre-swizzled global source (R12/R13-validated). Dense 128B lines.
__device__ __forceinline__ void stage_ht(const float4* __restrict__ gx_w,
                                         float4* R, int lane, int ht) {
#if USE_GLL
#pragma unroll
  for (int j = 0; j < 8; ++j) {
    const int cc = j * 8 + (lane >> 3);
    const int qq = lane & 7;
    const float4* g = gx_w + cc * 16 + ht * 8 + (qq ^ (cc & 7));
    __builtin_amdgcn_global_load_lds(
        (const __attribute__((address_space(1))) void*)g,
        (__attribute__((address_space(3))) void*)&R[j * 64], 16, 0, 0);
  }
#else
#pragma unroll
  for (int j = 0; j < 8; ++j) {
    const int cc = j * 8 + (lane >> 3);
    const int qq = lane & 7;
    R[j * 64 + lane] = gx_w[cc * 16 + ht * 8 + (qq ^ (cc & 7))];
  }
#endif
}

__global__ __launch_bounds__(P) void k_fused(const float* __restrict__ x,
                                             const float* __restrict__ bc,
                                             const float* __restrict__ ac,
                                             float* __restrict__ out) {
  __shared__ float4 arena[4096];      // 64KB: wave wv owns [wv*512, +512)
  __shared__ float  Msh[NMS][64];     // 1.75KB single copy (benign-race writes)
  __shared__ float  Bnd[8][8];        // wave-boundary inclusive states

  const int t    = threadIdx.x;
  const int lane = t & 63;
  const int wv   = t >> 6;
  const int swz  = lane & 7;
  float4* __restrict__ R = arena + (wv << 9);

  float b0[NS], b1[NS], b2[NS], a1[NS], a2[NS];
  load_coefs(bc, ac, b0, b1, b2, a1, a2);

  const float4* __restrict__ gx_w = reinterpret_cast<const float4*>(x) +
      (size_t)blockIdx.x * (P * LQ) + ((size_t)wv << 10);
  float4* __restrict__ gy_w = reinterpret_cast<float4*>(out) +
      (size_t)blockIdx.x * (P * LQ) + ((size_t)wv << 10);

  // ---- P1 HT0 staging (HBM latency hides under Ms squarings) ----
  stage_ht(gx_w, R, lane, 0);

  // ---- EVERY wave: Ms[d]=(A^64)^(2^d) in-register via __shfl; write the
  //      shared copy redundantly (identical values -> benign race) ----
  {
    const int r = lane >> 3, c = lane & 7;
    float p1[NS] = {0.f, 0.f, 0.f, 0.f};
    float p2[NS] = {0.f, 0.f, 0.f, 0.f};
    if (c & 1) p2[c >> 1] = 1.0f; else p1[c >> 1] = 1.0f;
    (void)step_cascade(0.0f, CO, p1, p2);
    float m = (r & 1) ? p2[r >> 1] : p1[r >> 1];  // A element (r,c)
#pragma unroll
    for (int it = 0; it < 12; ++it) {  // A^2..A^4096; M^(2^d) at it = 5+d
      float acc = 0.0f;
#pragma unroll
      for (int k = 0; k < NSTATE; ++k)
        acc = fmaf(__shfl(m, r * 8 + k), __shfl(m, k * 8 + c), acc);
      m = acc;
      if (it >= 5) Msh[it - 5][lane] = m;
    }
  }

  // ---- P1: chunk final state from zero, two half-tiles ----
  float s1[NS] = {0.f, 0.f, 0.f, 0.f};
  float s2[NS] = {0.f, 0.f, 0.f, 0.f};
  WAIT_VM0;
#pragma unroll
  for (int q = 0; q < 8; ++q) adv4(R[lane * 8 + (q ^ swz)], CO, s1, s2);
  WAIT_LGKM0;  // WAR: HT0 reads retired before HT1 overwrites
  stage_ht(gx_w, R, lane, 1);
  WAIT_VM0;
#pragma unroll
  for (int q = 0; q < 8; ++q) adv4(R[lane * 8 + (q ^ swz)], CO, s1, s2);

  float w[NSTATE];
#pragma unroll
  for (int k = 0; k < NS; ++k) { w[2 * k] = s1[k]; w[2 * k + 1] = s2[k]; }

  // ---- issue P4 HT0 staging NOW; the scan hides its latency ----
  WAIT_LGKM0;  // P1 HT1 ds_reads retired before gll overwrites region
  stage_ht(gx_w, R, lane, 0);

  // ---- in-wave Kogge-Stone levels 0..5 (shfl; own-wave Msh writes visible
  //      after the WAIT_LGKM0 above) ----
#pragma unroll
  for (int d = 0; d < 6; ++d) {
    const int off = 1 << d;
    const int src = (lane >= off) ? (lane - off) : lane;
    float prev[NSTATE];
#pragma unroll
    for (int r = 0; r < NSTATE; ++r) prev[r] = __shfl(w[r], src);
    if (lane >= off) {
#pragma unroll
      for (int r = 0; r < NSTATE; ++r) {
        float acc = w[r];
#pragma unroll
        for (int k = 0; k < NSTATE; ++k)
          acc = fmaf(Msh[d][r * 8 + k], prev[k], acc);  // uniform: broadcast
        w[r] = acc;
      }
    }
  }

  // ---- Bnd exchange: the ONE block barrier ----
  if (lane == 63) {
#pragma unroll
    for (int r = 0; r < NSTATE; ++r) Bnd[wv][r] = w[r];
  }
  __syncthreads();

  // ---- cross-wave prefix P_wv: fold Bnd[0..wv-1] through M^64 = Msh[6] ----
  float Pv[NSTATE] = {0.f, 0.f, 0.f, 0.f, 0.f, 0.f, 0.f, 0.f};
  for (int j = 0; j < wv; ++j) {  // wave-uniform trip count
    float np[NSTATE];
#pragma unroll
    for (int r = 0; r < NSTATE; ++r) {
      float acc = Bnd[j][r];
#pragma unroll
      for (int k = 0; k < NSTATE; ++k)
        acc = fmaf(Msh[6][r * 8 + k], Pv[k], acc);
      np[r] = acc;
    }
#pragma unroll
    for (int r = 0; r < NSTATE; ++r) Pv[r] = np[r];
  }

  // ---- z = M^lane * P (binary bits); s_init = u_excl_local + z ----
  float z[NSTATE];
#pragma unroll
  for (int r = 0; r < NSTATE; ++r) z[r] = Pv[r];
#pragma unroll
  for (int b = 0; b < 6; ++b) {
    float zb[NSTATE];
#pragma unroll
    for (int r = 0; r < NSTATE; ++r) {
      float acc = 0.0f;
#pragma unroll
      for (int k = 0; k < NSTATE; ++k)
        acc = fmaf(Msh[b][r * 8 + k], z[k], acc);
      zb[r] = acc;
    }
    const bool bit = (lane >> b) & 1;
#pragma unroll
    for (int r = 0; r < NSTATE; ++r) z[r] = bit ? zb[r] : z[r];
  }
  {
    const int esrc = lane ? lane - 1 : 0;
#pragma unroll
    for (int k = 0; k < NS; ++k) {
      const float ue0 = __shfl(w[2 * k], esrc);
      const float ue1 = __shfl(w[2 * k + 1], esrc);
      s1[k] = (lane ? ue0 : 0.0f) + z[2 * k];
      s2[k] = (lane ? ue1 : 0.0f) + z[2 * k + 1];
    }
  }

  // ---- P4: replay from exact init (R13's exact strict sequence) ----
#pragma unroll
  for (int ht = 0; ht < 2; ++ht) {
    if (ht == 1) stage_ht(gx_w, R, lane, 1);  // HT0 already staged pre-scan
    WAIT_VM0;
#pragma unroll
    for (int q = 0; q < 8; ++q) {
      const int s = lane * 8 + (q ^ swz);
      R[s] = out4(R[s], CO, s1, s2);  // in-place: own slots only
    }
    WAIT_LGKM0;  // in-place writes committed before transpose-out reads
#pragma unroll
    for (int j = 0; j < 8; ++j) {
      const int cc = j * 8 + (lane >> 3);
      const int qq = lane & 7;
      const float4 v = R[j * 64 + lane];
      gy_w[cc * 16 + ht * 8 + (qq ^ (cc & 7))] = v;  // dense 128B lines
    }
    if (ht == 0) WAIT_LGKM0;  // WAR: store-side ds_reads done before HT1 staging
  }
}

extern "C" void kernel_launch(void* const* d_in, const int* in_sizes, int n_in,
                              void* d_out, int out_size, void* d_ws, size_t ws_size,
                              hipStream_t stream) {
  const float* x  = (const float*)d_in[0];  // (B, T, 1)
  const float* bc = (const float*)d_in[1];  // (NS, 3)
  const float* ac = (const float*)d_in[2];  // (NS, 2)
  float* out = (float*)d_out;               // (B, T, 1)

  k_fused<<<BATCH, P, 0, stream>>>(x, bc, ac, out);
}